// Round 15
// baseline (278.239 us; speedup 1.0000x reference)
//
#include <hip/hip_runtime.h>
#include <stdint.h>
#include <stddef.h>

// ---------------------------------------------------------------------------
// 4 GAE encoders, fp16 MFMA. r13 configuration (anchor, 258.8us) with ONE
// isolated change: fused-s1's adjacency cast moves 2 chunks (64B) per thread
// per K-iter and completes in the first 12 of 24 iterations (was 1 chunk x 24
// iters). Doubles cast in-flight bytes; halves barrier-crossings per byte.
//   prep2 : X1,X2 -> fp16 padded (8-deep ILP, 576 blk x 2 iter) + 12 W^T
//   step1 : P16 = W1t @ Xh^T (S=4)  ||  adj cast (768 blk, 2 chunks/iter)
//   step2 : P16 = Adj @ T1^T  (S=4);  Z1 = reduce P16
//   step3 : T2 = tanh(W2t @ Z1^T)     (direct)
//   step4 : P16 = Adj @ T2^T  (S=8);  Z2 = reduce P16
//   step5 : T3 = W3t @ Z2^T           (direct)
//   step6 : P16 = Adj @ T3^T  (S=8);  Z3 = reduce P16
//   step7 : OUT = sigmoid(Z3 @ Z3^T), K=64  (fp32 NT stores)
// d_out layout: [4 x fp16 Adj 75.5 MB][fp16 split-K partials <=25.2 MB]
// (both dead before step7 overwrites d_out).
// ---------------------------------------------------------------------------

typedef __attribute__((ext_vector_type(8))) _Float16 half8;
typedef __attribute__((ext_vector_type(4))) float f32x4;

#define PAD 3072
#define MR  3000
#define SQ_STRIDE ((size_t)PAD * PAD)
#define UPA (PAD * PAD / 8)          // 32B chunks per padded array
#define CAST_BLK 576
#define WT_BLK   128

static __device__ __forceinline__ void async_cp16(const _Float16* g, _Float16* l) {
    __builtin_amdgcn_global_load_lds((const __attribute__((address_space(1))) void*)g,
                                     (__attribute__((address_space(3))) void*)l, 16, 0, 0);
}

// ---------------- prep2: X casts (8-deep ILP) + weight transposes ----------
struct PrepArgs {
    const float* csrc[2];  _Float16* cdst[2];   // X1,X2
    const float* Wsrc[12]; _Float16* Wdst[3];   // W1t, W2t, W3t bases
};

__global__ __launch_bounds__(256) void prep2(PrepArgs p) {
    __shared__ _Float16 lt[64 * 64];
    const int b = blockIdx.x;
    const int t = threadIdx.x;
    if (b < CAST_BLK) {
        // fp32 [3000][3000] -> fp16 [3072][3072] zero-padded; 2 iters/block.
        const int TOT = 2 * UPA;
        for (int base = b * 2048; base < TOT; base += CAST_BLK * 2048) {
            f32x4 v[8][2];
            #pragma unroll
            for (int k = 0; k < 8; ++k) {
                const int u   = base + (k << 8) + t;
                const int arr = u / UPA;
                const int rem = u - arr * UPA;
                const int row = rem / 384;
                const int c0  = (rem - row * 384) * 8;
                if (row < MR && c0 < MR) {
                    const float* sp = p.csrc[arr] + (size_t)row * MR + c0;
                    v[k][0] = __builtin_nontemporal_load((const f32x4*)sp);
                    v[k][1] = __builtin_nontemporal_load((const f32x4*)(sp + 4));
                } else {
                    v[k][0] = (f32x4){0.f, 0.f, 0.f, 0.f};
                    v[k][1] = (f32x4){0.f, 0.f, 0.f, 0.f};
                }
            }
            #pragma unroll
            for (int k = 0; k < 8; ++k) {
                const int u   = base + (k << 8) + t;
                const int arr = u / UPA;
                const int rem = u - arr * UPA;
                const int row = rem / 384;
                const int c0  = (rem - row * 384) * 8;
                half8 h;
                #pragma unroll
                for (int j = 0; j < 4; ++j) {
                    h[j]     = (_Float16)v[k][0][j];
                    h[4 + j] = (_Float16)v[k][1][j];
                }
                *(half8*)(p.cdst[arr] + (size_t)row * PAD + c0) = h;
            }
        }
    } else {
        // weight transpose-cast: src [fi][fo] fp32 -> dst [fo_pad][ldk] fp16
        for (int tile = b - CAST_BLK; tile < 816; tile += WT_BLK) {
            const int enc = tile / 204;
            int rem = tile - enc * 204;
            const float* src; _Float16* dst; int fi, fo, ldk, kt, rt;
            if (rem < 192) {
                src = p.Wsrc[enc * 3 + 0]; dst = p.Wdst[0] + (size_t)enc * 256 * PAD;
                fi = MR; fo = 256; ldk = PAD; kt = rem >> 2; rt = rem & 3;
            } else if (rem < 200) {
                rem -= 192;
                src = p.Wsrc[enc * 3 + 1]; dst = p.Wdst[1] + (size_t)enc * 128 * 256;
                fi = 256; fo = 128; ldk = 256; kt = rem >> 1; rt = rem & 1;
            } else {
                rem -= 200;
                src = p.Wsrc[enc * 3 + 2]; dst = p.Wdst[2] + (size_t)enc * 128 * 128;
                fi = 128; fo = 64; ldk = 128; kt = rem >> 1; rt = rem & 1;
            }
            const int k0 = kt * 64, r0 = rt * 64;
            __syncthreads();
            {
                const int kr = t >> 2, cc = (t & 3) << 4;
                const int gk = k0 + kr;
                const bool kok = gk < fi;
                #pragma unroll
                for (int j = 0; j < 16; ++j) {
                    const int gr = r0 + cc + j;
                    const float v = (kok && gr < fo) ? src[(size_t)gk * fo + gr] : 0.f;
                    lt[(cc + j) * 64 + kr] = (_Float16)v;
                }
            }
            __syncthreads();
            {
                const int rr = t >> 2, kk = (t & 3) << 4;
                half8 a  = *(half8*)&lt[rr * 64 + kk];
                half8 bb = *(half8*)&lt[rr * 64 + kk + 8];
                _Float16* dp = dst + (size_t)(r0 + rr) * ldk + k0 + kk;
                *(half8*)dp = a;
                *(half8*)(dp + 8) = bb;
            }
        }
    }
}

// ---------------- GEMM: C = A @ B^T, BK=32 double-buffered ----------------
struct GArgs {
    const _Float16* Aall; size_t aStride; int aMask;
    const _Float16* Ball; size_t bStride; int bMask;
    void* Call; size_t cStride;
    int M, Ncols, Kp, lda, ldb, ldc, mBound, nBound;
};
struct CastA { const float* src[4]; _Float16* dst; };

// OMODE: 0 = direct fp16 (opt tanh via ACT), 1 = fp16 partial z-indexed
//        (LDS repack, half8 stores), 2 = fp32 sigmoid (LDS repack, NT stores).
// S = split-K.  CAST = fused adjacency cast, 2 chunks/thread/iter over the
// first nht/2 iterations (grid must satisfy blocks*(nht/2)*256*2 == 4*UPA).
template<int ACT, int OMODE, int S, int CAST>
__global__ __launch_bounds__(256, 3)
void gemm_bt(GArgs ga, CastA ca)
{
    // smem: [2 bufs][ As:128x32 | Bs:128x32 ] fp16 = 32 KB total
    __shared__ _Float16 smem[16384];

    const int z   = blockIdx.z;
    const int e   = z / S;
    const int ksl = z - e * S;
    const int Kslice = ga.Kp / S;
    const int kbase  = ksl * Kslice;

    const _Float16* A = ga.Aall + (size_t)(e & ga.aMask) * ga.aStride;
    const _Float16* B = ga.Ball + (size_t)(e & ga.bMask) * ga.bStride;

    const int tm = blockIdx.x * 128;
    const int tn = blockIdx.y * 128;
    const int t    = threadIdx.x;
    const int lane = t & 63;
    const int w    = t >> 6;
    const int wm   = (w >> 1) * 64;
    const int wn   = (w & 1) * 64;
    const int lr   = lane & 15;
    const int lg   = lane >> 4;

    const int sr  = t >> 2;
    const int sch = t & 3;

    f32x4 acc[4][4];
    const f32x4 zero = {0.f, 0.f, 0.f, 0.f};
    #pragma unroll
    for (int i = 0; i < 4; ++i)
        #pragma unroll
        for (int j = 0; j < 4; ++j) acc[i][j] = zero;

    const int nht = Kslice >> 5;   // half-tiles of K=32
    const int nc  = nht >> 1;      // cast-active iterations (first half)

    const int fid = blockIdx.x + gridDim.x * (blockIdx.y + gridDim.y * blockIdx.z);
    f32x4 cv0, cv1, cv2, cv3;
    _Float16* cdp = nullptr;

    auto STAGE = [&](int ht, int buf) {
        const int k0 = kbase + (ht << 5);
        _Float16* As = smem + buf * 8192;
        _Float16* Bs = As + 4096;
        #pragma unroll
        for (int i = 0; i < 2; ++i) {
            const int row = sr + i * 64;
            const int sc  = sch ^ (row & 3);
            async_cp16(A + (size_t)(tm + row) * ga.lda + k0 + sc * 8,
                       As + (row * 4 + sch) * 8);
        }
        #pragma unroll
        for (int i = 0; i < 2; ++i) {
            const int row = sr + i * 64;
            const int sc  = sch ^ (row & 3);
            async_cp16(B + (size_t)(tn + row) * ga.ldb + k0 + sc * 8,
                       Bs + (row * 4 + sch) * 8);
        }
    };

    STAGE(0, 0);
    __syncthreads();
    for (int h = 0; h < nht; ++h) {
        const int cur = h & 1;
        if (h + 1 < nht) STAGE(h + 1, cur ^ 1);
        if (CAST) {
            // store pair h-1 (loads drained by the previous barrier)
            if (h > 0 && h <= nc) {
                half8 ha, hb;
                #pragma unroll
                for (int j = 0; j < 4; ++j) {
                    ha[j] = (_Float16)cv0[j]; ha[4 + j] = (_Float16)cv1[j];
                    hb[j] = (_Float16)cv2[j]; hb[4 + j] = (_Float16)cv3[j];
                }
                *(half8*)cdp = ha;
                *(half8*)(cdp + 8) = hb;
            }
            // issue pair h loads (64B contiguous; pair never crosses a row)
            if (h < nc) {
                const int u0   = ((fid * nc + h) * 256 + t) * 2;
                const int arr  = u0 / UPA;
                const int rem  = u0 - arr * UPA;
                const int crow = rem / 384;
                const int cc0  = (rem - crow * 384) * 8;
                cdp = ca.dst + (size_t)arr * SQ_STRIDE + (size_t)crow * PAD + cc0;
                const float* sp = ca.src[arr] + (size_t)crow * MR + cc0;
                if (crow < MR && cc0 < MR) {
                    cv0 = __builtin_nontemporal_load((const f32x4*)sp);
                    cv1 = __builtin_nontemporal_load((const f32x4*)(sp + 4));
                } else {
                    cv0 = (f32x4){0.f, 0.f, 0.f, 0.f};
                    cv1 = (f32x4){0.f, 0.f, 0.f, 0.f};
                }
                if (crow < MR && cc0 + 8 < MR) {
                    cv2 = __builtin_nontemporal_load((const f32x4*)(sp + 8));
                    cv3 = __builtin_nontemporal_load((const f32x4*)(sp + 12));
                } else {
                    cv2 = (f32x4){0.f, 0.f, 0.f, 0.f};
                    cv3 = (f32x4){0.f, 0.f, 0.f, 0.f};
                }
            }
        }
        const _Float16* As = smem + cur * 8192;
        const _Float16* Bs = As + 4096;
        half8 af[4], bf[4];
        #pragma unroll
        for (int mi = 0; mi < 4; ++mi) {
            const int ra = wm + mi * 16 + lr;
            const int ch = lg ^ (ra & 3);
            af[mi] = *(const half8*)(As + ra * 32 + ch * 8);
        }
        #pragma unroll
        for (int ni = 0; ni < 4; ++ni) {
            const int rb = wn + ni * 16 + lr;
            const int ch = lg ^ (rb & 3);
            bf[ni] = *(const half8*)(Bs + rb * 32 + ch * 8);
        }
        #pragma unroll
        for (int mi = 0; mi < 4; ++mi)
            #pragma unroll
            for (int ni = 0; ni < 4; ++ni)
                acc[mi][ni] = __builtin_amdgcn_mfma_f32_16x16x32_f16(
                    af[mi], bf[ni], acc[mi][ni], 0, 0, 0);
        __syncthreads();
    }

    // epilogue. D layout: col = lane&15, row = 4*(lane>>4)+reg (m89-verified).
    if (OMODE == 0) {
        _Float16* C = (_Float16*)ga.Call + (size_t)e * ga.cStride;
        #pragma unroll
        for (int mi = 0; mi < 4; ++mi)
            #pragma unroll
            for (int rr = 0; rr < 4; ++rr) {
                const int m = tm + wm + mi * 16 + lg * 4 + rr;
                #pragma unroll
                for (int ni = 0; ni < 4; ++ni) {
                    const int n = tn + wn + ni * 16 + lr;
                    float x = acc[mi][ni][rr];
                    if (ACT) x = tanhf(x);
                    const bool ok = (m < ga.M) && (n < ga.Ncols);
                    C[(size_t)m * ga.ldc + n] = ok ? (_Float16)x : (_Float16)0.f;
                }
            }
    } else if (OMODE == 1) {
        _Float16* Cp = (_Float16*)ga.Call + (size_t)z * ga.cStride;
        _Float16* ep = smem + w * 2048;
        #pragma unroll
        for (int hs = 0; hs < 2; ++hs) {
            __syncthreads();
            #pragma unroll
            for (int mi2 = 0; mi2 < 2; ++mi2)
                #pragma unroll
                for (int ni = 0; ni < 4; ++ni)
                    #pragma unroll
                    for (int rr = 0; rr < 4; ++rr) {
                        const int row = mi2 * 16 + lg * 4 + rr;
                        const int col = ni * 16 + lr;
                        const int sw  = (((row ^ (row >> 2)) & 3) << 4);
                        ep[row * 64 + (col ^ sw)] = (_Float16)acc[hs * 2 + mi2][ni][rr];
                    }
            __syncthreads();
            #pragma unroll
            for (int it = 0; it < 4; ++it) {
                const int row = it * 8 + (lane >> 3);
                const int c0  = (lane & 7) * 8;
                const int sw  = (((row ^ (row >> 2)) & 3) << 4);
                half8 v = *(const half8*)&ep[row * 64 + (c0 ^ sw)];
                const int gm = tm + wm + hs * 32 + row;
                const int gn = tn + wn + c0;
                *(half8*)&Cp[(size_t)gm * ga.ldc + gn] = v;
            }
        }
    } else {
        float* Cp = (float*)ga.Call + (size_t)e * ga.cStride;
        float* ep = (float*)smem + w * 2048;
        #pragma unroll
        for (int hs = 0; hs < 2; ++hs) {
            __syncthreads();
            #pragma unroll
            for (int mi2 = 0; mi2 < 2; ++mi2)
                #pragma unroll
                for (int ni = 0; ni < 4; ++ni)
                    #pragma unroll
                    for (int rr = 0; rr < 4; ++rr) {
                        const int row = mi2 * 16 + lg * 4 + rr;
                        const int col = ni * 16 + lr;
                        const int sw  = (((row ^ (row >> 2)) & 3) << 4);
                        ep[row * 64 + (col ^ sw)] = acc[hs * 2 + mi2][ni][rr];
                    }
            __syncthreads();
            #pragma unroll
            for (int r2 = 0; r2 < 8; ++r2) {
                const int row = r2 * 4 + (lane >> 4);
                const int c4  = (lane & 15) * 4;
                const int sw  = (((row ^ (row >> 2)) & 3) << 4);
                f32x4 v = *(const f32x4*)&ep[row * 64 + (c4 ^ sw)];
                const int gm = tm + wm + hs * 32 + row;
                const int gn = tn + wn + c4;
                if (gm < ga.mBound && gn < ga.nBound) {
                    #pragma unroll
                    for (int j = 0; j < 4; ++j)
                        v[j] = 1.0f / (1.0f + __expf(-v[j]));
                    __builtin_nontemporal_store(v, (f32x4*)&Cp[(size_t)gm * ga.ldc + gn]);
                }
            }
        }
    }
}

// ---------------- split-K reduce: out = act(sum_s P16[s]) in fp16 ----------
template<int ACT, int S>
__global__ __launch_bounds__(256)
void reduce_k(const _Float16* __restrict__ P, _Float16* __restrict__ out, size_t region)
{
    const size_t e    = blockIdx.y;
    const size_t base = (size_t)(blockIdx.x * 256 + threadIdx.x) * 8;
    const _Float16* p0 = P + e * S * region + base;
    float s[8] = {0.f, 0.f, 0.f, 0.f, 0.f, 0.f, 0.f, 0.f};
    #pragma unroll
    for (int si = 0; si < S; ++si) {
        half8 v = *(const half8*)(p0 + (size_t)si * region);
        #pragma unroll
        for (int j = 0; j < 8; ++j) s[j] += (float)v[j];
    }
    half8 h;
    #pragma unroll
    for (int j = 0; j < 8; ++j) {
        float x = s[j];
        if (ACT) x = tanhf(x);
        h[j] = (_Float16)x;
    }
    *(half8*)(out + e * region + base) = h;
}

// ---------------- launcher ----------------
extern "C" void kernel_launch(void* const* d_in, const int* in_sizes, int n_in,
                              void* d_out, int out_size, void* d_ws, size_t ws_size,
                              hipStream_t stream)
{
    const size_t R1 = 786432;   // 256*3072 and 3072*256
    const size_t R2 = 393216;   // 128*3072 and 3072*128

    // d_out layout: [4 x fp16 Adj (75.5 MB)][fp16 partials (<=25.2 MB)]
    _Float16* Adj    = (_Float16*)d_out;
    _Float16* Part16 = Adj + 4 * SQ_STRIDE;

    _Float16* hb = (_Float16*)d_ws;
    size_t off = 0;
    auto alloc = [&](size_t elems) { _Float16* p = hb + off; off += elems; return p; };
    _Float16* Xh  = alloc(2 * SQ_STRIDE);
    _Float16* T1  = alloc(4 * R1);
    _Float16* Z1  = alloc(4 * R1);
    _Float16* T2  = alloc(4 * R2);
    _Float16* Z2  = alloc(4 * R2);
    _Float16* T3  = alloc(4 * R2);
    _Float16* Z3  = alloc(4 * R2);
    _Float16* W1t = alloc(4ull * 256 * PAD);
    _Float16* W2t = alloc(4ull * 128 * 256);
    _Float16* W3t = alloc(4ull * 128 * 128);

    // prep: X casts + weight transposes
    PrepArgs pa;
    pa.csrc[0] = (const float*)d_in[0]; pa.cdst[0] = Xh;
    pa.csrc[1] = (const float*)d_in[1]; pa.cdst[1] = Xh + SQ_STRIDE;
    for (int enc = 0; enc < 4; ++enc)
        for (int li = 0; li < 3; ++li)
            pa.Wsrc[enc * 3 + li] = (const float*)d_in[6 + enc * 3 + li];
    pa.Wdst[0] = W1t; pa.Wdst[1] = W2t; pa.Wdst[2] = W3t;
    prep2<<<dim3(CAST_BLK + WT_BLK, 1, 1), 256, 0, stream>>>(pa);

    const int BIG = 1 << 30;
    CastA cnone = { { nullptr, nullptr, nullptr, nullptr }, nullptr };

    // step1 (fused): P16 = W1t @ Xh^T  (M=256 N=3072 K=3072, S=4)
    //                + adj cast: 768 blk * 12 iters * 256 thr * 2 == 4*UPA
    GArgs g1 = { W1t, (size_t)256 * PAD, 3, Xh, SQ_STRIDE, 1,
                 Part16, R1, 256, PAD, PAD, PAD, PAD, PAD, BIG, BIG };
    CastA ca;
    for (int i = 0; i < 4; ++i) ca.src[i] = (const float*)d_in[2 + i];
    ca.dst = Adj;
    gemm_bt<0, 1, 4, 1><<<dim3(2, 24, 16), 256, 0, stream>>>(g1, ca);
    reduce_k<1, 4><<<dim3(384, 4, 1), 256, 0, stream>>>(Part16, T1, R1);

    // step2: P16 = Adj @ T1^T  M=3072 N=256 K=3072, S=4
    GArgs g2 = { Adj, SQ_STRIDE, 3, T1, R1, 3,
                 Part16, R1, PAD, 256, PAD, PAD, PAD, 256, BIG, BIG };
    gemm_bt<0, 1, 4, 0><<<dim3(24, 2, 16), 256, 0, stream>>>(g2, cnone);
    reduce_k<0, 4><<<dim3(384, 4, 1), 256, 0, stream>>>(Part16, Z1, R1);

    // step3: T2 = tanh(W2t @ Z1^T)  M=128 N=3072 K=256, direct
    GArgs g3 = { W2t, (size_t)128 * 256, 3, Z1, R1, 3,
                 T2, R2, 128, PAD, 256, 256, 256, PAD, BIG, BIG };
    gemm_bt<1, 0, 1, 0><<<dim3(1, 24, 4), 256, 0, stream>>>(g3, cnone);

    // step4: P16 = Adj @ T2^T  M=3072 N=128 K=3072, S=8
    GArgs g4 = { Adj, SQ_STRIDE, 3, T2, R2, 3,
                 Part16, R2, PAD, 128, PAD, PAD, PAD, 128, BIG, BIG };
    gemm_bt<0, 1, 8, 0><<<dim3(24, 1, 32), 256, 0, stream>>>(g4, cnone);
    reduce_k<0, 8><<<dim3(192, 4, 1), 256, 0, stream>>>(Part16, Z2, R2);

    // step5: T3 = W3t @ Z2^T  M=128 N=3072 K=128, direct
    GArgs g5 = { W3t, (size_t)128 * 128, 3, Z2, R2, 3,
                 T3, R2, 128, PAD, 128, 128, 128, PAD, BIG, BIG };
    gemm_bt<0, 0, 1, 0><<<dim3(1, 24, 4), 256, 0, stream>>>(g5, cnone);

    // step6: P16 = Adj @ T3^T  M=3072 N=128 K=3072, S=8
    GArgs g6 = { Adj, SQ_STRIDE, 3, T3, R2, 3,
                 Part16, R2, PAD, 128, PAD, PAD, PAD, 128, BIG, BIG };
    gemm_bt<0, 1, 8, 0><<<dim3(24, 1, 32), 256, 0, stream>>>(g6, cnone);
    reduce_k<0, 8><<<dim3(192, 4, 1), 256, 0, stream>>>(Part16, Z3, R2);

    // step7: OUT = sigmoid(Z3 @ Z3^T)  M=N=3000 K=64 (cols 64..127 of Z3 zero)
    GArgs g7 = { Z3, R2, 3, Z3, R2, 3,
                 d_out, (size_t)MR * MR, MR, MR, 64, 128, 128, MR, MR, MR };
    gemm_bt<0, 2, 1, 0><<<dim3(24, 24, 4), 256, 0, stream>>>(g7, cnone);
}

// Round 16
// 257.826 us; speedup vs baseline: 1.0792x; 1.0792x over previous
//
#include <hip/hip_runtime.h>
#include <stdint.h>
#include <stddef.h>

// ---------------------------------------------------------------------------
// 4 GAE encoders, fp16 MFMA. r13 configuration (anchor, 258.8us) with ONE
// isolated change: corrected BK=32 LDS swizzle. Old `^ (row&3)` gave 4-way
// bank conflicts (rows alias banks every 2 at 64B stride; only 4 of 8 16B
// positions used -> SQ_LDS_BANK_CONFLICT=2.46M measured r15). New
// `^ ((row>>1)&3)` covers all 8 positions -> exactly 2-way (free, m136).
//   prep2 : X1,X2 -> fp16 padded (8-deep ILP, 576 blk x 2 iter) + 12 W^T
//   step1 : P16 = W1t @ Xh^T (S=4)  ||  adj fp32 -> fp16 cast (768 blk, exact)
//   step2 : P16 = Adj @ T1^T  (S=4);  Z1 = reduce P16
//   step3 : T2 = tanh(W2t @ Z1^T)     (direct)
//   step4 : P16 = Adj @ T2^T  (S=8);  Z2 = reduce P16
//   step5 : T3 = W3t @ Z2^T           (direct)
//   step6 : P16 = Adj @ T3^T  (S=8);  Z3 = reduce P16
//   step7 : OUT = sigmoid(Z3 @ Z3^T), K=64  (fp32 NT stores)
// d_out layout: [4 x fp16 Adj 75.5 MB][fp16 split-K partials <=25.2 MB]
// (both dead before step7 overwrites d_out).
// ---------------------------------------------------------------------------

typedef __attribute__((ext_vector_type(8))) _Float16 half8;
typedef __attribute__((ext_vector_type(4))) float f32x4;

#define PAD 3072
#define MR  3000
#define SQ_STRIDE ((size_t)PAD * PAD)
#define UPA (PAD * PAD / 8)          // 32B chunks per padded array
#define CAST_BLK 576
#define WT_BLK   128

static __device__ __forceinline__ void async_cp16(const _Float16* g, _Float16* l) {
    __builtin_amdgcn_global_load_lds((const __attribute__((address_space(1))) void*)g,
                                     (__attribute__((address_space(3))) void*)l, 16, 0, 0);
}

// ---------------- prep2: X casts (8-deep ILP) + weight transposes ----------
struct PrepArgs {
    const float* csrc[2];  _Float16* cdst[2];   // X1,X2
    const float* Wsrc[12]; _Float16* Wdst[3];   // W1t, W2t, W3t bases
};

__global__ __launch_bounds__(256) void prep2(PrepArgs p) {
    __shared__ _Float16 lt[64 * 64];
    const int b = blockIdx.x;
    const int t = threadIdx.x;
    if (b < CAST_BLK) {
        // fp32 [3000][3000] -> fp16 [3072][3072] zero-padded; 2 iters/block.
        const int TOT = 2 * UPA;
        for (int base = b * 2048; base < TOT; base += CAST_BLK * 2048) {
            f32x4 v[8][2];
            #pragma unroll
            for (int k = 0; k < 8; ++k) {
                const int u   = base + (k << 8) + t;
                const int arr = u / UPA;
                const int rem = u - arr * UPA;
                const int row = rem / 384;
                const int c0  = (rem - row * 384) * 8;
                if (row < MR && c0 < MR) {
                    const float* sp = p.csrc[arr] + (size_t)row * MR + c0;
                    v[k][0] = __builtin_nontemporal_load((const f32x4*)sp);
                    v[k][1] = __builtin_nontemporal_load((const f32x4*)(sp + 4));
                } else {
                    v[k][0] = (f32x4){0.f, 0.f, 0.f, 0.f};
                    v[k][1] = (f32x4){0.f, 0.f, 0.f, 0.f};
                }
            }
            #pragma unroll
            for (int k = 0; k < 8; ++k) {
                const int u   = base + (k << 8) + t;
                const int arr = u / UPA;
                const int rem = u - arr * UPA;
                const int row = rem / 384;
                const int c0  = (rem - row * 384) * 8;
                half8 h;
                #pragma unroll
                for (int j = 0; j < 4; ++j) {
                    h[j]     = (_Float16)v[k][0][j];
                    h[4 + j] = (_Float16)v[k][1][j];
                }
                *(half8*)(p.cdst[arr] + (size_t)row * PAD + c0) = h;
            }
        }
    } else {
        // weight transpose-cast: src [fi][fo] fp32 -> dst [fo_pad][ldk] fp16
        for (int tile = b - CAST_BLK; tile < 816; tile += WT_BLK) {
            const int enc = tile / 204;
            int rem = tile - enc * 204;
            const float* src; _Float16* dst; int fi, fo, ldk, kt, rt;
            if (rem < 192) {
                src = p.Wsrc[enc * 3 + 0]; dst = p.Wdst[0] + (size_t)enc * 256 * PAD;
                fi = MR; fo = 256; ldk = PAD; kt = rem >> 2; rt = rem & 3;
            } else if (rem < 200) {
                rem -= 192;
                src = p.Wsrc[enc * 3 + 1]; dst = p.Wdst[1] + (size_t)enc * 128 * 256;
                fi = 256; fo = 128; ldk = 256; kt = rem >> 1; rt = rem & 1;
            } else {
                rem -= 200;
                src = p.Wsrc[enc * 3 + 2]; dst = p.Wdst[2] + (size_t)enc * 128 * 128;
                fi = 128; fo = 64; ldk = 128; kt = rem >> 1; rt = rem & 1;
            }
            const int k0 = kt * 64, r0 = rt * 64;
            __syncthreads();
            {
                const int kr = t >> 2, cc = (t & 3) << 4;
                const int gk = k0 + kr;
                const bool kok = gk < fi;
                #pragma unroll
                for (int j = 0; j < 16; ++j) {
                    const int gr = r0 + cc + j;
                    const float v = (kok && gr < fo) ? src[(size_t)gk * fo + gr] : 0.f;
                    lt[(cc + j) * 64 + kr] = (_Float16)v;
                }
            }
            __syncthreads();
            {
                const int rr = t >> 2, kk = (t & 3) << 4;
                half8 a  = *(half8*)&lt[rr * 64 + kk];
                half8 bb = *(half8*)&lt[rr * 64 + kk + 8];
                _Float16* dp = dst + (size_t)(r0 + rr) * ldk + k0 + kk;
                *(half8*)dp = a;
                *(half8*)(dp + 8) = bb;
            }
        }
    }
}

// ---------------- GEMM: C = A @ B^T, BK=32 double-buffered ----------------
struct GArgs {
    const _Float16* Aall; size_t aStride; int aMask;
    const _Float16* Ball; size_t bStride; int bMask;
    void* Call; size_t cStride;
    int M, Ncols, Kp, lda, ldb, ldc, mBound, nBound;
};
struct CastA { const float* src[4]; _Float16* dst; };

// OMODE: 0 = direct fp16 (opt tanh via ACT), 1 = fp16 partial z-indexed
//        (LDS repack, half8 stores), 2 = fp32 sigmoid (LDS repack, NT stores).
// S = split-K.  CAST = also convert the 4 fp32 adjacencies to fp16 (step1).
template<int ACT, int OMODE, int S, int CAST>
__global__ __launch_bounds__(256, 3)
void gemm_bt(GArgs ga, CastA ca)
{
    // smem: [2 bufs][ As:128x32 | Bs:128x32 ] fp16 = 32 KB total
    __shared__ _Float16 smem[16384];

    const int z   = blockIdx.z;
    const int e   = z / S;
    const int ksl = z - e * S;
    const int Kslice = ga.Kp / S;
    const int kbase  = ksl * Kslice;

    const _Float16* A = ga.Aall + (size_t)(e & ga.aMask) * ga.aStride;
    const _Float16* B = ga.Ball + (size_t)(e & ga.bMask) * ga.bStride;

    const int tm = blockIdx.x * 128;
    const int tn = blockIdx.y * 128;
    const int t    = threadIdx.x;
    const int lane = t & 63;
    const int w    = t >> 6;
    const int wm   = (w >> 1) * 64;
    const int wn   = (w & 1) * 64;
    const int lr   = lane & 15;
    const int lg   = lane >> 4;

    // staging coords: 512 chunk-slots of 16 B per operand per half-tile
    const int sr  = t >> 2;    // row (first 64), +64 on second iter
    const int sch = t & 3;     // 16B chunk within 32-half row

    f32x4 acc[4][4];
    const f32x4 zero = {0.f, 0.f, 0.f, 0.f};
    #pragma unroll
    for (int i = 0; i < 4; ++i)
        #pragma unroll
        for (int j = 0; j < 4; ++j) acc[i][j] = zero;

    const int nht = Kslice >> 5;   // half-tiles of K=32

    // fused-cast state (CAST=1: grid must satisfy blocks*nht*256 == 4*UPA)
    const int fid = blockIdx.x + gridDim.x * (blockIdx.y + gridDim.y * blockIdx.z);
    f32x4 cv0, cv1;
    _Float16* cdp = nullptr;

    auto STAGE = [&](int ht, int buf) {
        const int k0 = kbase + (ht << 5);
        _Float16* As = smem + buf * 8192;
        _Float16* Bs = As + 4096;
        #pragma unroll
        for (int i = 0; i < 2; ++i) {
            const int row = sr + i * 64;
            const int sc  = sch ^ ((row >> 1) & 3);   // conflict-free swizzle
            async_cp16(A + (size_t)(tm + row) * ga.lda + k0 + sc * 8,
                       As + (row * 4 + sch) * 8);
        }
        #pragma unroll
        for (int i = 0; i < 2; ++i) {
            const int row = sr + i * 64;
            const int sc  = sch ^ ((row >> 1) & 3);
            async_cp16(B + (size_t)(tn + row) * ga.ldb + k0 + sc * 8,
                       Bs + (row * 4 + sch) * 8);
        }
    };

    STAGE(0, 0);
    __syncthreads();
    for (int h = 0; h < nht; ++h) {
        const int cur = h & 1;
        if (h + 1 < nht) STAGE(h + 1, cur ^ 1);   // overlap with compute below
        if (CAST) {
            // store chunk h-1 (its loads were drained by the previous barrier)
            if (h > 0) {
                half8 hh;
                #pragma unroll
                for (int j = 0; j < 4; ++j) {
                    hh[j] = (_Float16)cv0[j]; hh[4 + j] = (_Float16)cv1[j];
                }
                *(half8*)cdp = hh;
            }
            // issue chunk h loads (complete by this iteration's barrier)
            const int g    = (fid * nht + h) * 256 + t;
            const int arr  = g / UPA;
            const int rem  = g - arr * UPA;
            const int crow = rem / 384;
            const int cc0  = (rem - crow * 384) * 8;
            cdp = ca.dst + (size_t)arr * SQ_STRIDE + (size_t)crow * PAD + cc0;
            if (crow < MR && cc0 < MR) {
                const float* sp = ca.src[arr] + (size_t)crow * MR + cc0;
                cv0 = __builtin_nontemporal_load((const f32x4*)sp);
                cv1 = __builtin_nontemporal_load((const f32x4*)(sp + 4));
            } else {
                cv0 = (f32x4){0.f, 0.f, 0.f, 0.f};
                cv1 = (f32x4){0.f, 0.f, 0.f, 0.f};
            }
        }
        const _Float16* As = smem + cur * 8192;
        const _Float16* Bs = As + 4096;
        half8 af[4], bf[4];
        #pragma unroll
        for (int mi = 0; mi < 4; ++mi) {
            const int ra = wm + mi * 16 + lr;
            const int ch = lg ^ ((ra >> 1) & 3);   // conflict-free swizzle
            af[mi] = *(const half8*)(As + ra * 32 + ch * 8);
        }
        #pragma unroll
        for (int ni = 0; ni < 4; ++ni) {
            const int rb = wn + ni * 16 + lr;
            const int ch = lg ^ ((rb >> 1) & 3);
            bf[ni] = *(const half8*)(Bs + rb * 32 + ch * 8);
        }
        #pragma unroll
        for (int mi = 0; mi < 4; ++mi)
            #pragma unroll
            for (int ni = 0; ni < 4; ++ni)
                acc[mi][ni] = __builtin_amdgcn_mfma_f32_16x16x32_f16(
                    af[mi], bf[ni], acc[mi][ni], 0, 0, 0);
        __syncthreads();   // drains vmcnt (next buf + cast loads ready)
    }
    if (CAST) {   // final chunk store
        half8 hh;
        #pragma unroll
        for (int j = 0; j < 4; ++j) {
            hh[j] = (_Float16)cv0[j]; hh[4 + j] = (_Float16)cv1[j];
        }
        *(half8*)cdp = hh;
    }

    // epilogue. D layout: col = lane&15, row = 4*(lane>>4)+reg (m89-verified).
    if (OMODE == 0) {
        _Float16* C = (_Float16*)ga.Call + (size_t)e * ga.cStride;
        #pragma unroll
        for (int mi = 0; mi < 4; ++mi)
            #pragma unroll
            for (int rr = 0; rr < 4; ++rr) {
                const int m = tm + wm + mi * 16 + lg * 4 + rr;
                #pragma unroll
                for (int ni = 0; ni < 4; ++ni) {
                    const int n = tn + wn + ni * 16 + lr;
                    float x = acc[mi][ni][rr];
                    if (ACT) x = tanhf(x);
                    const bool ok = (m < ga.M) && (n < ga.Ncols);
                    C[(size_t)m * ga.ldc + n] = ok ? (_Float16)x : (_Float16)0.f;
                }
            }
    } else if (OMODE == 1) {
        _Float16* Cp = (_Float16*)ga.Call + (size_t)z * ga.cStride;
        _Float16* ep = smem + w * 2048;
        #pragma unroll
        for (int hs = 0; hs < 2; ++hs) {
            __syncthreads();
            #pragma unroll
            for (int mi2 = 0; mi2 < 2; ++mi2)
                #pragma unroll
                for (int ni = 0; ni < 4; ++ni)
                    #pragma unroll
                    for (int rr = 0; rr < 4; ++rr) {
                        const int row = mi2 * 16 + lg * 4 + rr;
                        const int col = ni * 16 + lr;
                        const int sw  = (((row ^ (row >> 2)) & 3) << 4);
                        ep[row * 64 + (col ^ sw)] = (_Float16)acc[hs * 2 + mi2][ni][rr];
                    }
            __syncthreads();
            #pragma unroll
            for (int it = 0; it < 4; ++it) {
                const int row = it * 8 + (lane >> 3);
                const int c0  = (lane & 7) * 8;
                const int sw  = (((row ^ (row >> 2)) & 3) << 4);
                half8 v = *(const half8*)&ep[row * 64 + (c0 ^ sw)];
                const int gm = tm + wm + hs * 32 + row;
                const int gn = tn + wn + c0;
                *(half8*)&Cp[(size_t)gm * ga.ldc + gn] = v;
            }
        }
    } else {
        float* Cp = (float*)ga.Call + (size_t)e * ga.cStride;
        float* ep = (float*)smem + w * 2048;
        #pragma unroll
        for (int hs = 0; hs < 2; ++hs) {
            __syncthreads();
            #pragma unroll
            for (int mi2 = 0; mi2 < 2; ++mi2)
                #pragma unroll
                for (int ni = 0; ni < 4; ++ni)
                    #pragma unroll
                    for (int rr = 0; rr < 4; ++rr) {
                        const int row = mi2 * 16 + lg * 4 + rr;
                        const int col = ni * 16 + lr;
                        const int sw  = (((row ^ (row >> 2)) & 3) << 4);
                        ep[row * 64 + (col ^ sw)] = acc[hs * 2 + mi2][ni][rr];
                    }
            __syncthreads();
            #pragma unroll
            for (int r2 = 0; r2 < 8; ++r2) {
                const int row = r2 * 4 + (lane >> 4);
                const int c4  = (lane & 15) * 4;
                const int sw  = (((row ^ (row >> 2)) & 3) << 4);
                f32x4 v = *(const f32x4*)&ep[row * 64 + (c4 ^ sw)];
                const int gm = tm + wm + hs * 32 + row;
                const int gn = tn + wn + c4;
                if (gm < ga.mBound && gn < ga.nBound) {
                    #pragma unroll
                    for (int j = 0; j < 4; ++j)
                        v[j] = 1.0f / (1.0f + __expf(-v[j]));
                    __builtin_nontemporal_store(v, (f32x4*)&Cp[(size_t)gm * ga.ldc + gn]);
                }
            }
        }
    }
}

// ---------------- split-K reduce: out = act(sum_s P16[s]) in fp16 ----------
template<int ACT, int S>
__global__ __launch_bounds__(256)
void reduce_k(const _Float16* __restrict__ P, _Float16* __restrict__ out, size_t region)
{
    const size_t e    = blockIdx.y;
    const size_t base = (size_t)(blockIdx.x * 256 + threadIdx.x) * 8;
    const _Float16* p0 = P + e * S * region + base;
    float s[8] = {0.f, 0.f, 0.f, 0.f, 0.f, 0.f, 0.f, 0.f};
    #pragma unroll
    for (int si = 0; si < S; ++si) {
        half8 v = *(const half8*)(p0 + (size_t)si * region);
        #pragma unroll
        for (int j = 0; j < 8; ++j) s[j] += (float)v[j];
    }
    half8 h;
    #pragma unroll
    for (int j = 0; j < 8; ++j) {
        float x = s[j];
        if (ACT) x = tanhf(x);
        h[j] = (_Float16)x;
    }
    *(half8*)(out + e * region + base) = h;
}

// ---------------- launcher ----------------
extern "C" void kernel_launch(void* const* d_in, const int* in_sizes, int n_in,
                              void* d_out, int out_size, void* d_ws, size_t ws_size,
                              hipStream_t stream)
{
    const size_t R1 = 786432;   // 256*3072 and 3072*256
    const size_t R2 = 393216;   // 128*3072 and 3072*128

    // d_out layout: [4 x fp16 Adj (75.5 MB)][fp16 partials (<=25.2 MB)]
    _Float16* Adj    = (_Float16*)d_out;
    _Float16* Part16 = Adj + 4 * SQ_STRIDE;

    _Float16* hb = (_Float16*)d_ws;
    size_t off = 0;
    auto alloc = [&](size_t elems) { _Float16* p = hb + off; off += elems; return p; };
    _Float16* Xh  = alloc(2 * SQ_STRIDE);
    _Float16* T1  = alloc(4 * R1);
    _Float16* Z1  = alloc(4 * R1);
    _Float16* T2  = alloc(4 * R2);
    _Float16* Z2  = alloc(4 * R2);
    _Float16* T3  = alloc(4 * R2);
    _Float16* Z3  = alloc(4 * R2);
    _Float16* W1t = alloc(4ull * 256 * PAD);
    _Float16* W2t = alloc(4ull * 128 * 256);
    _Float16* W3t = alloc(4ull * 128 * 128);

    // prep: X casts + weight transposes
    PrepArgs pa;
    pa.csrc[0] = (const float*)d_in[0]; pa.cdst[0] = Xh;
    pa.csrc[1] = (const float*)d_in[1]; pa.cdst[1] = Xh + SQ_STRIDE;
    for (int enc = 0; enc < 4; ++enc)
        for (int li = 0; li < 3; ++li)
            pa.Wsrc[enc * 3 + li] = (const float*)d_in[6 + enc * 3 + li];
    pa.Wdst[0] = W1t; pa.Wdst[1] = W2t; pa.Wdst[2] = W3t;
    prep2<<<dim3(CAST_BLK + WT_BLK, 1, 1), 256, 0, stream>>>(pa);

    const int BIG = 1 << 30;
    CastA cnone = { { nullptr, nullptr, nullptr, nullptr }, nullptr };

    // step1 (fused): P16 = W1t @ Xh^T  (M=256 N=3072 K=3072, S=4)
    //                + adjacency cast: 768 blk * 24 iters * 256 thr == 4*UPA
    GArgs g1 = { W1t, (size_t)256 * PAD, 3, Xh, SQ_STRIDE, 1,
                 Part16, R1, 256, PAD, PAD, PAD, PAD, PAD, BIG, BIG };
    CastA ca;
    for (int i = 0; i < 4; ++i) ca.src[i] = (const float*)d_in[2 + i];
    ca.dst = Adj;
    gemm_bt<0, 1, 4, 1><<<dim3(2, 24, 16), 256, 0, stream>>>(g1, ca);
    reduce_k<1, 4><<<dim3(384, 4, 1), 256, 0, stream>>>(Part16, T1, R1);

    // step2: P16 = Adj @ T1^T  M=3072 N=256 K=3072, S=4
    GArgs g2 = { Adj, SQ_STRIDE, 3, T1, R1, 3,
                 Part16, R1, PAD, 256, PAD, PAD, PAD, 256, BIG, BIG };
    gemm_bt<0, 1, 4, 0><<<dim3(24, 2, 16), 256, 0, stream>>>(g2, cnone);
    reduce_k<0, 4><<<dim3(384, 4, 1), 256, 0, stream>>>(Part16, Z1, R1);

    // step3: T2 = tanh(W2t @ Z1^T)  M=128 N=3072 K=256, direct
    GArgs g3 = { W2t, (size_t)128 * 256, 3, Z1, R1, 3,
                 T2, R2, 128, PAD, 256, 256, 256, PAD, BIG, BIG };
    gemm_bt<1, 0, 1, 0><<<dim3(1, 24, 4), 256, 0, stream>>>(g3, cnone);

    // step4: P16 = Adj @ T2^T  M=3072 N=128 K=3072, S=8
    GArgs g4 = { Adj, SQ_STRIDE, 3, T2, R2, 3,
                 Part16, R2, PAD, 128, PAD, PAD, PAD, 128, BIG, BIG };
    gemm_bt<0, 1, 8, 0><<<dim3(24, 1, 32), 256, 0, stream>>>(g4, cnone);
    reduce_k<0, 8><<<dim3(192, 4, 1), 256, 0, stream>>>(Part16, Z2, R2);

    // step5: T3 = W3t @ Z2^T  M=128 N=3072 K=128, direct
    GArgs g5 = { W3t, (size_t)128 * 128, 3, Z2, R2, 3,
                 T3, R2, 128, PAD, 128, 128, 128, PAD, BIG, BIG };
    gemm_bt<0, 0, 1, 0><<<dim3(1, 24, 4), 256, 0, stream>>>(g5, cnone);

    // step6: P16 = Adj @ T3^T  M=3072 N=128 K=3072, S=8
    GArgs g6 = { Adj, SQ_STRIDE, 3, T3, R2, 3,
                 Part16, R2, PAD, 128, PAD, PAD, PAD, 128, BIG, BIG };
    gemm_bt<0, 1, 8, 0><<<dim3(24, 1, 32), 256, 0, stream>>>(g6, cnone);
    reduce_k<0, 8><<<dim3(192, 4, 1), 256, 0, stream>>>(Part16, Z3, R2);

    // step7: OUT = sigmoid(Z3 @ Z3^T)  M=N=3000 K=64 (cols 64..127 of Z3 zero)
    GArgs g7 = { Z3, R2, 3, Z3, R2, 3,
                 d_out, (size_t)MR * MR, MR, MR, 64, 128, 128, MR, MR, MR };
    gemm_bt<0, 2, 1, 0><<<dim3(24, 24, 4), 256, 0, stream>>>(g7, cnone);
}